// Round 1
// baseline (1118.868 us; speedup 1.0000x reference)
//
#include <hip/hip_runtime.h>
#include <hip/hip_bf16.h>

// Indexer hard-forward: out[i,:] = items[min(floor(clamp(idx[i],0,1)*N_ITEMS), N_ITEMS-1), :]
// N = 1048576 rows, N_ITEMS = 1024, D = 256 (f32).
// Memory-bound: ~1 GiB of output writes dominates. One wave per row,
// float4 per lane (64 lanes x 16 B = 1024 B = one full row per instruction).

#define N_ITEMS_C 1024
#define D_ITEM_C  256

__global__ __launch_bounds__(256) void indexer_gather_kernel(
    const float* __restrict__ indices,
    const float* __restrict__ items,
    float* __restrict__ out,
    int n_rows)
{
    const int gtid   = blockIdx.x * blockDim.x + threadIdx.x;
    const int wave   = gtid >> 6;            // global wave id
    const int lane   = threadIdx.x & 63;     // lane within wave
    const int nwaves = (gridDim.x * blockDim.x) >> 6;

    for (int r = wave; r < n_rows; r += nwaves) {
        // wave-uniform index load (hardware broadcast)
        float f = indices[r];
        f = fminf(fmaxf(f, 0.0f), 1.0f);
        int c = (int)floorf(f * (float)N_ITEMS_C);
        c = min(c, N_ITEMS_C - 1);

        // lane l moves bytes [16l, 16l+16) of the 1024-byte row
        const float4 v = *reinterpret_cast<const float4*>(
            items + (size_t)c * D_ITEM_C + (lane << 2));
        *reinterpret_cast<float4*>(
            out + (size_t)r * D_ITEM_C + (lane << 2)) = v;
    }
}

extern "C" void kernel_launch(void* const* d_in, const int* in_sizes, int n_in,
                              void* d_out, int out_size, void* d_ws, size_t ws_size,
                              hipStream_t stream) {
    const float* indices = (const float*)d_in[0];
    const float* items   = (const float*)d_in[1];
    float* out           = (float*)d_out;

    const int n_rows = in_sizes[0];          // 1048576

    // Memory-bound: cap grid, grid-stride the rest (Guideline 11).
    const int block = 256;
    const int grid  = 2048;                  // 8192 waves -> 128 rows/wave

    indexer_gather_kernel<<<grid, block, 0, stream>>>(indices, items, out, n_rows);
}